// Round 1
// baseline (369.617 us; speedup 1.0000x reference)
//
#include <hip/hip_runtime.h>

// DiscriminativeLoss — B=8, D=32, N from in_sizes, K=64 instance bins.
// Two passes over x (segment means, then hinged L1 variance) + tiny finalize.

#define IGNORE_IDX (-100)

constexpr int B = 8;
constexpr int D = 32;
constexpr int K = 64;
constexpr float DELTA_V = 0.5f;
constexpr float TWO_DELTA_D = 3.0f;   // 2 * DELTA_D
constexpr float PARAM_REG = 0.001f;

constexpr int BK  = B * K;            // 512
constexpr int BKD = B * K * D;        // 16384

// ws float layout: [0,BK) counts | [BK, BK+BKD) sums | [BK+BKD, BK+BKD+BK) var_seg

// ---------------------------------------------------------------- K1: segment sums
__global__ __launch_bounds__(256) void k1_segsum(
    const float* __restrict__ x, const int* __restrict__ sem,
    const int* __restrict__ inst, float* __restrict__ ws,
    int N, int blocksPerBatch)
{
    __shared__ float s_sums[K][D + 1];   // stride 33 -> bank (k+d)%32
    __shared__ float s_counts[K];

    const int b     = blockIdx.x / blocksPerBatch;
    const int chunk = blockIdx.x - b * blocksPerBatch;

    for (int i = threadIdx.x; i < K * (D + 1); i += 256) (&s_sums[0][0])[i] = 0.f;
    for (int i = threadIdx.x; i < K; i += 256) s_counts[i] = 0.f;
    __syncthreads();

    const int pts = N / blocksPerBatch;
    const int n0  = chunk * pts;
    const float* xb    = x    + (size_t)b * D * N + n0;
    const int*   semb  = sem  + (size_t)b * N + n0;
    const int*   instb = inst + (size_t)b * N + n0;

    for (int base = threadIdx.x * 4; base + 3 < pts; base += 256 * 4) {
        const int4 c4 = *(const int4*)(semb + base);
        const int4 i4 = *(const int4*)(instb + base);
        const int cl[4] = {c4.x, c4.y, c4.z, c4.w};
        const int il[4] = {i4.x, i4.y, i4.z, i4.w};
        int  id[4];
        bool v[4];
#pragma unroll
        for (int j = 0; j < 4; ++j) {
            v[j]  = (cl[j] != IGNORE_IDX);
            int t = (cl[j] == 1) ? 0 : il[j];
            id[j] = (t < 0) ? 0 : (t > K - 1 ? K - 1 : t);
        }
#pragma unroll
        for (int j = 0; j < 4; ++j)
            if (v[j]) atomicAdd(&s_counts[id[j]], 1.f);
#pragma unroll
        for (int d = 0; d < D; ++d) {
            const float4 xv = *(const float4*)(xb + (size_t)d * N + base);
            const float xf[4] = {xv.x, xv.y, xv.z, xv.w};
#pragma unroll
            for (int j = 0; j < 4; ++j)
                if (v[j]) atomicAdd(&s_sums[id[j]][d], xf[j]);
        }
    }
    __syncthreads();

    float* g_counts = ws;
    float* g_sums   = ws + BK;
    for (int i = threadIdx.x; i < K * D; i += 256) {
        const int k = i >> 5, d = i & 31;
        const float s = s_sums[k][d];
        if (s != 0.f) atomicAdd(&g_sums[(size_t)b * K * D + i], s);
    }
    for (int i = threadIdx.x; i < K; i += 256) {
        const float c = s_counts[i];
        if (c != 0.f) atomicAdd(&g_counts[b * K + i], c);
    }
}

// ---------------------------------------------------------------- K3: variance pass
__global__ __launch_bounds__(256) void k3_var(
    const float* __restrict__ x, const int* __restrict__ sem,
    const int* __restrict__ inst, float* __restrict__ ws,
    int N, int blocksPerBatch)
{
    __shared__ float s_mu[K][D + 1];
    __shared__ float s_var[K];

    const int b     = blockIdx.x / blocksPerBatch;
    const int chunk = blockIdx.x - b * blocksPerBatch;

    const float* g_counts = ws;
    const float* g_sums   = ws + BK;

    for (int i = threadIdx.x; i < K * D; i += 256) {
        const int k = i >> 5, d = i & 31;
        s_mu[k][d] = g_sums[(size_t)b * K * D + i] / (g_counts[b * K + k] + 1e-8f);
    }
    for (int i = threadIdx.x; i < K; i += 256) s_var[i] = 0.f;
    __syncthreads();

    const int pts = N / blocksPerBatch;
    const int n0  = chunk * pts;
    const float* xb    = x    + (size_t)b * D * N + n0;
    const int*   semb  = sem  + (size_t)b * N + n0;
    const int*   instb = inst + (size_t)b * N + n0;

    for (int base = threadIdx.x * 4; base + 3 < pts; base += 256 * 4) {
        const int4 c4 = *(const int4*)(semb + base);
        const int4 i4 = *(const int4*)(instb + base);
        const int cl[4] = {c4.x, c4.y, c4.z, c4.w};
        const int il[4] = {i4.x, i4.y, i4.z, i4.w};
        int  id[4];
        bool v[4];
#pragma unroll
        for (int j = 0; j < 4; ++j) {
            v[j]  = (cl[j] != IGNORE_IDX);
            int t = (cl[j] == 1) ? 0 : il[j];
            id[j] = (t < 0) ? 0 : (t > K - 1 ? K - 1 : t);
        }
        float dist[4] = {0.f, 0.f, 0.f, 0.f};
#pragma unroll
        for (int d = 0; d < D; ++d) {
            const float4 xv = *(const float4*)(xb + (size_t)d * N + base);
            const float xf[4] = {xv.x, xv.y, xv.z, xv.w};
#pragma unroll
            for (int j = 0; j < 4; ++j)
                dist[j] += fabsf(xf[j] - s_mu[id[j]][d]);
        }
#pragma unroll
        for (int j = 0; j < 4; ++j) {
            if (v[j]) {
                const float h = fmaxf(dist[j] - DELTA_V, 0.f);
                if (h > 0.f) atomicAdd(&s_var[id[j]], h * h);
            }
        }
    }
    __syncthreads();

    float* g_var = ws + BK + BKD;
    for (int i = threadIdx.x; i < K; i += 256) {
        const float s = s_var[i];
        if (s != 0.f) atomicAdd(&g_var[b * K + i], s);
    }
}

// ---------------------------------------------------------------- K4: per-batch finalize
__device__ float block_reduce_sum(float v, float* s_buf) {
    for (int o = 32; o > 0; o >>= 1) v += __shfl_down(v, o, 64);
    const int wid  = threadIdx.x >> 6;
    const int lane = threadIdx.x & 63;
    if (lane == 0) s_buf[wid] = v;
    __syncthreads();
    float r = 0.f;
    if (threadIdx.x == 0)
        for (int w = 0; w < 8; ++w) r += s_buf[w];
    __syncthreads();
    return r;   // valid on thread 0 only
}

__global__ __launch_bounds__(512) void k4_final(const float* __restrict__ ws,
                                                float* __restrict__ out)
{
    const int b = blockIdx.x;
    const float* g_counts = ws + b * K;
    const float* g_sums   = ws + BK + (size_t)b * K * D;
    const float* g_var    = ws + BK + BKD + b * K;

    __shared__ float s_mu[K][D + 1];
    __shared__ float s_cnt[K];
    __shared__ float s_present[K];
    __shared__ float s_red[8];

    const int t = threadIdx.x;
    for (int i = t; i < K; i += 512) {
        const float c = g_counts[i];
        s_cnt[i]     = c;
        s_present[i] = (c > 0.f) ? 1.f : 0.f;
    }
    __syncthreads();
    for (int i = t; i < K * D; i += 512) {
        const int k = i >> 5, d = i & 31;
        s_mu[k][d] = g_sums[i] / (s_cnt[k] + 1e-8f);
    }
    __syncthreads();

    // pairwise distance hinge (ordered pairs i != j, both present)
    float distPart = 0.f;
    for (int p = t; p < K * K; p += 512) {
        const int i = p >> 6, j = p & 63;
        if (i != j && s_present[i] > 0.f && s_present[j] > 0.f) {
            float dsum = 0.f;
#pragma unroll
            for (int d = 0; d < D; ++d) dsum += fabsf(s_mu[i][d] - s_mu[j][d]);
            const float h = fmaxf(TWO_DELTA_D - dsum, 0.f);
            distPart += h * h;
        }
    }
    // reg
    float regPart = 0.f;
    for (int i = t; i < K * D; i += 512) {
        const int k = i >> 5;
        if (s_present[k] > 0.f) regPart += fabsf(s_mu[k][i & 31]);
    }
    // var (normalized per cluster)
    float varPart = 0.f;
    for (int k = t; k < K; k += 512) varPart += g_var[k] / (s_cnt[k] + 1e-8f);
    // n present
    float npPart = 0.f;
    for (int k = t; k < K; k += 512) npPart += s_present[k];

    const float distSum = block_reduce_sum(distPart, s_red);
    const float regSum  = block_reduce_sum(regPart,  s_red);
    const float varSum  = block_reduce_sum(varPart,  s_red);
    const float npSum   = block_reduce_sum(npPart,   s_red);

    if (t == 0) {
        const float n_inst = fmaxf(npSum, 1.0f);
        const float npairs = npSum * npSum - npSum;   // ordered present pairs
        const float l_var  = varSum / n_inst;
        const float l_dist = (npairs > 0.f) ? (distSum / fmaxf(npairs, 1.0f)) : 0.f;
        const float l_reg  = PARAM_REG * (regSum / n_inst);
        const float loss   = l_var + l_dist + l_reg;
        const float invB   = 1.0f / (float)B;
        atomicAdd(out + 0, loss   * invB);
        atomicAdd(out + 1, l_var  * invB);
        atomicAdd(out + 2, l_dist * invB);
        atomicAdd(out + 3, l_reg  * invB);
    }
}

// ---------------------------------------------------------------- launch
extern "C" void kernel_launch(void* const* d_in, const int* in_sizes, int n_in,
                              void* d_out, int out_size, void* d_ws, size_t ws_size,
                              hipStream_t stream) {
    const float* x    = (const float*)d_in[0];
    const int*   sem  = (const int*)d_in[1];
    const int*   inst = (const int*)d_in[2];
    float*       ws   = (float*)d_ws;
    float*       out  = (float*)d_out;

    const int N = in_sizes[1] / B;
    const int blocksPerBatch = 64;

    hipMemsetAsync(ws, 0, (size_t)(BK + BKD + BK) * sizeof(float), stream);
    hipMemsetAsync(out, 0, (size_t)out_size * sizeof(float), stream);

    k1_segsum<<<dim3(B * blocksPerBatch), dim3(256), 0, stream>>>(x, sem, inst, ws, N, blocksPerBatch);
    k3_var  <<<dim3(B * blocksPerBatch), dim3(256), 0, stream>>>(x, sem, inst, ws, N, blocksPerBatch);
    k4_final<<<dim3(B), dim3(512), 0, stream>>>(ws, out);
}